// Round 4
// baseline (147.943 us; speedup 1.0000x reference)
//
#include <hip/hip_runtime.h>
#include <math.h>

#define NS 512
#define DE 512
#define NCL 5
#define KSPLIT 16                  // 16 tiles x 16 K-splits = 256 blocks
#define PART_ELEMS (KSPLIT * NS * NS)
#define NBLK 256

// ctrl layout (u32 words): [0]=gsum(f32) [1]=gnz [2]=bar [3]=ticket

// ---------------------------------------------------------------------------
// K1 (prologue): rn[r] = 1/max(||pred[r]||,1e-8); block 0 zeroes ctrl words.
// Stream order guarantees ctrl==0 before k_fused regardless of ws poison state.
// ---------------------------------------------------------------------------
__global__ __launch_bounds__(256) void k_norm(const float* __restrict__ pred,
                                              float* __restrict__ rn,
                                              unsigned int* __restrict__ ctrl) {
    const int tid = threadIdx.x;
    if (blockIdx.x == 0 && tid < 4) ctrl[tid] = 0u;
    const int w = tid >> 6, lane = tid & 63;
    const float4* p4 = (const float4*)pred;
#pragma unroll
    for (int rr = 0; rr < 2; rr++) {
        const int r = blockIdx.x * 8 + w * 2 + rr;
        float4 a = p4[r * (DE / 4) + lane];
        float4 b = p4[r * (DE / 4) + 64 + lane];
        float ss = a.x * a.x + a.y * a.y + a.z * a.z + a.w * a.w
                 + b.x * b.x + b.y * b.y + b.z * b.z + b.w * b.w;
#pragma unroll
        for (int m = 32; m >= 1; m >>= 1) ss += __shfl_xor(ss, m, 64);
        if (lane == 0) rn[r] = 1.0f / fmaxf(sqrtf(ss), 1e-8f);
    }
}

// ---------------------------------------------------------------------------
// K2 (fused persistent): phase 1 = split-K gram partial (128x128 tile, K=32,
// XOR-swizzled float4 LDS); grid barrier; phase 2 = loss for anchors 2b,2b+1;
// ticket finalize writes out.
// ---------------------------------------------------------------------------
union SMem {
    struct { float4 As4[128][8]; float4 Bs4[128][8]; } g;          // 32 KB
    struct {
        float4 v4s[NS / 4];
        float  ck[NS];
        int    pk[NS];
        float  spart[NS * 17];
        float  redf[256];
        int    redi[256];
        unsigned int pcount;
    } l;                                                            // ~43 KB
};

__global__ __launch_bounds__(256) void k_fused(const float* __restrict__ pred,
                                               const float* __restrict__ rn,
                                               const int* __restrict__ target,
                                               const float* __restrict__ draw,
                                               float* __restrict__ part,
                                               unsigned int* __restrict__ ctrl,
                                               float* __restrict__ out) {
    __shared__ SMem sm;
    const int tid = threadIdx.x;
    const int b = blockIdx.x;

    // ================= phase 1: gram partial =================
    {
        const int t = b >> 4, z = b & 15;
        const int row0 = (t >> 2) * 128, col0 = (t & 3) * 128;
        const int kz0 = z * 32;

        const int lr = tid >> 1;
        const int sbase = (tid & 1) * 4;
        const int swz = (lr >> 3) & 7;
        const float4* gA = (const float4*)&pred[(row0 + lr) * DE + kz0];
        const float4* gB = (const float4*)&pred[(col0 + lr) * DE + kz0];
#pragma unroll
        for (int q = 0; q < 4; q++) {
            int s = sbase + q;
            sm.g.As4[lr][s ^ swz] = gA[s];
            sm.g.Bs4[lr][s ^ swz] = gB[s];
        }
        __syncthreads();

        const int tx = tid & 15, ty = tid >> 4;
        const int aswz = ty & 7, bswz = tx & 7;
        float acc[8][8] = {};
#pragma unroll
        for (int q = 0; q < 8; q++) {
            float4 b4[8];
#pragma unroll
            for (int c = 0; c < 8; c++) b4[c] = sm.g.Bs4[tx * 8 + c][q ^ bswz];
#pragma unroll
            for (int rr = 0; rr < 2; rr++) {
                float4 a4[4];
#pragma unroll
                for (int r = 0; r < 4; r++) a4[r] = sm.g.As4[ty * 8 + rr * 4 + r][q ^ aswz];
#pragma unroll
                for (int r = 0; r < 4; r++) {
#pragma unroll
                    for (int c = 0; c < 8; c++) {
                        float v = acc[rr * 4 + r][c];
                        v = fmaf(a4[r].x, b4[c].x, v);
                        v = fmaf(a4[r].y, b4[c].y, v);
                        v = fmaf(a4[r].z, b4[c].z, v);
                        v = fmaf(a4[r].w, b4[c].w, v);
                        acc[rr * 4 + r][c] = v;
                    }
                }
            }
        }
        float* op = part + (size_t)z * NS * NS;
#pragma unroll
        for (int m = 0; m < 8; m++) {
            float4 o0 = make_float4(acc[m][0], acc[m][1], acc[m][2], acc[m][3]);
            float4 o1 = make_float4(acc[m][4], acc[m][5], acc[m][6], acc[m][7]);
            float* dst = &op[(row0 + ty * 8 + m) * NS + col0 + tx * 8];
            *(float4*)dst = o0;
            *(float4*)(dst + 4) = o1;
        }
    }

    // ================= grid barrier =================
    {
        __threadfence();      // flush this thread's part-stores toward L3
        __syncthreads();      // all block threads fenced before arrival
        if (tid == 0) {
            unsigned int* bar = ctrl + 2;
            atomicAdd(bar, 1u);
            while (atomicAdd(bar, 0u) < (unsigned int)NBLK)
                __builtin_amdgcn_s_sleep(1);
        }
        __syncthreads();
        __threadfence();      // invalidate caches before reading remote data
    }

    // ================= phase 2: loss for anchors 2b, 2b+1 =================
    float cp[NCL];
    cp[0] = 0.0f;
#pragma unroll
    for (int c = 0; c < NCL - 1; c++) cp[c + 1] = cp[c] + log1pf(expf(draw[c]));

    float l_contrib = 0.0f;     // only tid0's copies are used
    unsigned int l_nz = 0u;

    for (int a = 0; a < 2; a++) {
        const int i = b * 2 + a;
        __syncthreads();
        if (tid == 0) sm.l.pcount = 0u;
        __syncthreads();

        const int ti = target[i];
        const float cpi = cp[ti];
        const float rni = rn[i];

        // cos row: sum 16 partial rows (float2/thread), scale by rn
        float2 g2 = make_float2(0.0f, 0.0f);
#pragma unroll
        for (int z = 0; z < KSPLIT; z++) {
            float2 t2 = ((const float2*)&part[(size_t)z * NS * NS + (size_t)i * NS])[tid];
            g2.x += t2.x; g2.y += t2.y;
        }
        const int j0 = tid * 2;
        float2 rnj = ((const float2*)rn)[tid];
        float c0 = g2.x * rni * rnj.x;
        float c1 = g2.y * rni * rnj.y;
        int tj0 = target[j0], tj1 = target[j0 + 1];
        bool n0 = (tj0 != ti), n1 = (tj1 != ti);
        sm.l.ck[j0] = c0; sm.l.ck[j0 + 1] = c1;
        float2 vv = make_float2(n0 ? (c0 + fabsf(cpi - cp[tj0])) : -1e30f,
                                n1 ? (c1 + fabsf(cpi - cp[tj1])) : -1e30f);
        ((float2*)sm.l.v4s)[tid] = vv;
        int ncnt = (n0 ? 1 : 0) + (n1 ? 1 : 0);
        if (!n0 && j0 != i)     sm.l.pk[atomicAdd(&sm.l.pcount, 1u)] = j0;
        if (!n1 && j0 + 1 != i) sm.l.pk[atomicAdd(&sm.l.pcount, 1u)] = j0 + 1;

        sm.l.redi[tid] = ncnt;
        __syncthreads();
        for (int s = 128; s > 0; s >>= 1) {
            if (tid < s) sm.l.redi[tid] += sm.l.redi[tid + s];
            __syncthreads();
        }
        const int negcount = sm.l.redi[0];
        const unsigned int npos = sm.l.pcount;
        __syncthreads();   // protect redi reuse

        // pass 1: 16 k-lanes x 16 j-chunks, 32 j's cached in VGPRs
        const int kl = tid & 15, jc = tid >> 4;
        float4 vj[8];
#pragma unroll
        for (int t = 0; t < 8; t++) vj[t] = sm.l.v4s[jc * 8 + t];

        for (unsigned int p = kl; p < npos; p += 16) {
            const float ckp = sm.l.ck[sm.l.pk[p]];
            float s0 = 0.0f, s1 = 0.0f;
#pragma unroll
            for (int t = 0; t < 8; t++) {
                float4 w = vj[t];
                s0 += fmaxf(w.x - ckp, 0.0f) + fmaxf(w.y - ckp, 0.0f);
                s1 += fmaxf(w.z - ckp, 0.0f) + fmaxf(w.w - ckp, 0.0f);
            }
            sm.l.spart[p * 17 + jc] = s0 + s1;
        }
        __syncthreads();

        // pass 2: assemble s[k]
        float ssum = 0.0f;
        int nzc = 0;
        for (unsigned int p = tid; p < npos; p += 256) {
            float s = 0.0f;
#pragma unroll
            for (int q = 0; q < 16; q++) s += sm.l.spart[p * 17 + q];
            ssum += s;
            if (s != 0.0f) nzc++;
        }
        sm.l.redf[tid] = ssum;
        sm.l.redi[tid] = nzc;
        __syncthreads();
        for (int s = 128; s > 0; s >>= 1) {
            if (tid < s) { sm.l.redf[tid] += sm.l.redf[tid + s]; sm.l.redi[tid] += sm.l.redi[tid + s]; }
            __syncthreads();
        }
        if (tid == 0) {
            int denom = negcount > 1 ? negcount : 1;
            l_contrib += sm.l.redf[0] / (float)denom;
            l_nz += (unsigned int)sm.l.redi[0];
        }
    }

    // ================= finalize =================
    if (tid == 0) {
        float* gsum = (float*)ctrl;
        unsigned int* gnz = ctrl + 1;
        unsigned int* ticket = ctrl + 3;
        if (l_contrib != 0.0f || l_nz != 0u) {
            atomicAdd(gsum, l_contrib);
            atomicAdd(gnz, l_nz);
        }
        __threadfence();
        unsigned int t = atomicAdd(ticket, 1u);
        if (t == (unsigned int)(NBLK - 1)) {
            float s = atomicAdd(gsum, 0.0f);
            unsigned int n = atomicAdd(gnz, 0u);
            out[0] = s / (float)(n > 1u ? n : 1u);
        }
    }
}

extern "C" void kernel_launch(void* const* d_in, const int* in_sizes, int n_in,
                              void* d_out, int out_size, void* d_ws, size_t ws_size,
                              hipStream_t stream) {
    const float* pred   = (const float*)d_in[0];
    const float* draw   = (const float*)d_in[1];
    const int*   target = (const int*)d_in[2];
    float* out = (float*)d_out;

    float* ws   = (float*)d_ws;
    float* part = ws;                                   // 16 MB
    float* rn   = ws + PART_ELEMS;                      // 512 floats
    unsigned int* ctrl = (unsigned int*)(rn + NS);      // 4 words

    hipLaunchKernelGGL(k_norm, dim3(64), dim3(256), 0, stream, pred, rn, ctrl);
    hipLaunchKernelGGL(k_fused, dim3(NBLK), dim3(256), 0, stream,
                       pred, rn, target, draw, part, ctrl, out);
}

// Round 5
// 99.312 us; speedup vs baseline: 1.4897x; 1.4897x over previous
//
#include <hip/hip_runtime.h>
#include <math.h>

#define NS 512
#define DE 512
#define NCL 5
#define KSPLIT 16          // gemm K-split: 16 partials of K=32
#define PART_ELEMS (KSPLIT * NS * NS)

// ctrl words: [0]=gsum(f32) [1]=gnz [2]=ticket [3]=spare

// ---------------------------------------------------------------------------
// K1: split-K Gram partials on RAW pred. grid (4,4,16), 128x128 tile, K=32
//     per block, 8x8 outputs/thread, XOR-swizzled float4 LDS (A broadcast,
//     B 2-way = free). Diagonal-tile blocks also emit dpart[z][row] = partial
//     ||row||^2 contribution. Block (0,0,0) zeroes ctrl (stream-ordered
//     before k_loss's atomics; other gemm blocks never touch ctrl).
// ---------------------------------------------------------------------------
__global__ __launch_bounds__(256, 1) void k_gemm(const float* __restrict__ pred,
                                                 float* __restrict__ part,
                                                 float* __restrict__ dpart,
                                                 unsigned int* __restrict__ ctrl) {
    const int tid = threadIdx.x;
    if (blockIdx.x == 0 && blockIdx.y == 0 && blockIdx.z == 0 && tid < 4) ctrl[tid] = 0u;

    __shared__ float4 As4[128][8];
    __shared__ float4 Bs4[128][8];

    const int row0 = blockIdx.y * 128, col0 = blockIdx.x * 128;
    const int z = blockIdx.z;
    const int kz0 = z * 32;

    const int lr = tid >> 1;
    const int sbase = (tid & 1) * 4;
    const int swz = (lr >> 3) & 7;
    const float4* gA = (const float4*)&pred[(row0 + lr) * DE + kz0];
    const float4* gB = (const float4*)&pred[(col0 + lr) * DE + kz0];
#pragma unroll
    for (int q = 0; q < 4; q++) {
        int s = sbase + q;
        As4[lr][s ^ swz] = gA[s];
        Bs4[lr][s ^ swz] = gB[s];
    }
    __syncthreads();

    const int tx = tid & 15, ty = tid >> 4;
    const int aswz = ty & 7, bswz = tx & 7;
    float acc[8][8] = {};

#pragma unroll
    for (int q = 0; q < 8; q++) {
        float4 b4[8];
#pragma unroll
        for (int c = 0; c < 8; c++) b4[c] = Bs4[tx * 8 + c][q ^ bswz];
#pragma unroll
        for (int rr = 0; rr < 2; rr++) {
            float4 a4[4];
#pragma unroll
            for (int r = 0; r < 4; r++) a4[r] = As4[ty * 8 + rr * 4 + r][q ^ aswz];
#pragma unroll
            for (int r = 0; r < 4; r++) {
#pragma unroll
                for (int c = 0; c < 8; c++) {
                    float v = acc[rr * 4 + r][c];
                    v = fmaf(a4[r].x, b4[c].x, v);
                    v = fmaf(a4[r].y, b4[c].y, v);
                    v = fmaf(a4[r].z, b4[c].z, v);
                    v = fmaf(a4[r].w, b4[c].w, v);
                    acc[rr * 4 + r][c] = v;
                }
            }
        }
    }

    float* op = part + (size_t)z * NS * NS;
#pragma unroll
    for (int m = 0; m < 8; m++) {
        float4 o0 = make_float4(acc[m][0], acc[m][1], acc[m][2], acc[m][3]);
        float4 o1 = make_float4(acc[m][4], acc[m][5], acc[m][6], acc[m][7]);
        float* dst = &op[(row0 + ty * 8 + m) * NS + col0 + tx * 8];
        *(float4*)dst = o0;
        *(float4*)(dst + 4) = o1;
    }

    // partial squared-norms from the Gram diagonal (free byproduct)
    if (blockIdx.x == blockIdx.y && ty == tx) {
#pragma unroll
        for (int m = 0; m < 8; m++)
            dpart[z * NS + row0 + ty * 8 + m] = acc[m][m];
    }
}

// ---------------------------------------------------------------------------
// K2: per-anchor loss + ticket finalize. Block i = anchor i.
//   rn[j]   = 1/max(sqrt(sum_z dpart[z][j]), 1e-8)
//   cos_ij  = (sum_z part_z[i,j]) * rn[i] * rn[j]
//   v[j]    = cos + |cp_i - cp_j| (negatives) else -1e30
//   s[k]    = sum_j relu(v[j]-cos_ik): 16 k-lanes x 16 j-chunks (j in VGPRs)
//   last block (ticket): out = gsum / max(gnz,1)
// ---------------------------------------------------------------------------
__global__ __launch_bounds__(256, 2) void k_loss(const float* __restrict__ part,
                                                 const float* __restrict__ dpart,
                                                 const int* __restrict__ target,
                                                 const float* __restrict__ draw,
                                                 unsigned int* __restrict__ ctrl,
                                                 float* __restrict__ out) {
    const int i = blockIdx.x;
    const int tid = threadIdx.x;

    __shared__ float4 v4s[NS / 4];
    __shared__ float  rn_s[NS];
    __shared__ float  ck[NS];
    __shared__ int    pk[NS];
    __shared__ float  spart[NS * 17];
    __shared__ float  redf[256];
    __shared__ int    redi[256];
    __shared__ unsigned int pcount;

    float* gsum = (float*)ctrl;
    unsigned int* gnz    = ctrl + 1;
    unsigned int* ticket = ctrl + 2;

    // row inverse-norms from summed diag partials (coalesced float2 rows)
    float2 d2 = make_float2(0.0f, 0.0f);
#pragma unroll
    for (int z = 0; z < KSPLIT; z++) {
        float2 t2 = ((const float2*)&dpart[z * NS])[tid];
        d2.x += t2.x; d2.y += t2.y;
    }
    const float rn0 = 1.0f / fmaxf(sqrtf(d2.x), 1e-8f);
    const float rn1 = 1.0f / fmaxf(sqrtf(d2.y), 1e-8f);
    const int j0 = tid * 2;
    rn_s[j0] = rn0; rn_s[j0 + 1] = rn1;
    if (tid == 0) pcount = 0u;

    // ordinal class positions
    float cp[NCL];
    cp[0] = 0.0f;
#pragma unroll
    for (int c = 0; c < NCL - 1; c++) cp[c + 1] = cp[c] + log1pf(expf(draw[c]));
    const int ti = target[i];
    const float cpi = cp[ti];
    __syncthreads();

    const float rni = rn_s[i];

    // cos row: sum 16 partial rows (float2/thread), scale by rn
    float2 g2 = make_float2(0.0f, 0.0f);
#pragma unroll
    for (int z = 0; z < KSPLIT; z++) {
        float2 t2 = ((const float2*)&part[(size_t)z * NS * NS + (size_t)i * NS])[tid];
        g2.x += t2.x; g2.y += t2.y;
    }
    float c0 = g2.x * rni * rn0;
    float c1 = g2.y * rni * rn1;
    int tj0 = target[j0], tj1 = target[j0 + 1];
    bool n0 = (tj0 != ti), n1 = (tj1 != ti);
    ck[j0] = c0; ck[j0 + 1] = c1;
    float2 vv = make_float2(n0 ? (c0 + fabsf(cpi - cp[tj0])) : -1e30f,
                            n1 ? (c1 + fabsf(cpi - cp[tj1])) : -1e30f);
    ((float2*)v4s)[tid] = vv;
    int ncnt = (n0 ? 1 : 0) + (n1 ? 1 : 0);
    if (!n0 && j0 != i)     pk[atomicAdd(&pcount, 1u)] = j0;
    if (!n1 && j0 + 1 != i) pk[atomicAdd(&pcount, 1u)] = j0 + 1;

    redi[tid] = ncnt;
    __syncthreads();
    for (int s = 128; s > 0; s >>= 1) {
        if (tid < s) redi[tid] += redi[tid + s];
        __syncthreads();
    }
    const int negcount = redi[0];
    const unsigned int npos = pcount;
    __syncthreads();   // protect redi reuse

    // pass 1: 16 k-lanes x 16 j-chunks; 32 j's cached in VGPRs
    const int kl = tid & 15, jc = tid >> 4;
    float4 vj[8];
#pragma unroll
    for (int t = 0; t < 8; t++) vj[t] = v4s[jc * 8 + t];

    for (unsigned int p = kl; p < npos; p += 16) {
        const float ckp = ck[pk[p]];
        float s0 = 0.0f, s1 = 0.0f;
#pragma unroll
        for (int t = 0; t < 8; t++) {
            float4 w = vj[t];
            s0 += fmaxf(w.x - ckp, 0.0f) + fmaxf(w.y - ckp, 0.0f);
            s1 += fmaxf(w.z - ckp, 0.0f) + fmaxf(w.w - ckp, 0.0f);
        }
        spart[p * 17 + jc] = s0 + s1;
    }
    __syncthreads();

    // pass 2: assemble s[k], accumulate sum + nonzero count
    float ssum = 0.0f;
    int nzc = 0;
    for (unsigned int p = tid; p < npos; p += 256) {
        float s = 0.0f;
#pragma unroll
        for (int q = 0; q < 16; q++) s += spart[p * 17 + q];
        ssum += s;
        if (s != 0.0f) nzc++;
    }

    redf[tid] = ssum;
    redi[tid] = nzc;
    __syncthreads();
    for (int s = 128; s > 0; s >>= 1) {
        if (tid < s) { redf[tid] += redf[tid + s]; redi[tid] += redi[tid + s]; }
        __syncthreads();
    }
    if (tid == 0) {
        int denom = negcount > 1 ? negcount : 1;
        if (redf[0] != 0.0f || redi[0] != 0) {
            atomicAdd(gsum, redf[0] / (float)denom);
            atomicAdd(gnz, (unsigned int)redi[0]);
        }
        __threadfence();
        unsigned int t = atomicAdd(ticket, 1u);
        if (t == (unsigned int)(gridDim.x - 1)) {
            float s = atomicAdd(gsum, 0.0f);
            unsigned int n = atomicAdd(gnz, 0u);
            out[0] = s / (float)(n > 1u ? n : 1u);
        }
    }
}

extern "C" void kernel_launch(void* const* d_in, const int* in_sizes, int n_in,
                              void* d_out, int out_size, void* d_ws, size_t ws_size,
                              hipStream_t stream) {
    const float* pred   = (const float*)d_in[0];
    const float* draw   = (const float*)d_in[1];
    const int*   target = (const int*)d_in[2];
    float* out = (float*)d_out;

    float* ws    = (float*)d_ws;
    float* part  = ws;                                  // 16 MB
    float* dpart = ws + PART_ELEMS;                     // 16*512 floats
    unsigned int* ctrl = (unsigned int*)(dpart + KSPLIT * NS);  // 4 words

    hipLaunchKernelGGL(k_gemm, dim3(4, 4, KSPLIT), dim3(256), 0, stream,
                       pred, part, dpart, ctrl);
    hipLaunchKernelGGL(k_loss, dim3(NS), dim3(256), 0, stream,
                       part, dpart, target, draw, ctrl, out);
}

// Round 6
// 91.217 us; speedup vs baseline: 1.6219x; 1.0887x over previous
//
#include <hip/hip_runtime.h>
#include <math.h>

#define NS 512
#define DE 512
#define NCL 5
#define KSPLIT 16          // gemm K-split: 16 partials of K=32
#define PART_ELEMS (KSPLIT * NS * NS)

// ctrl words: [0]=gsum(f32) [1]=gnz [2]=ticket [3]=spare

// ---------------------------------------------------------------------------
// K1: split-K Gram partials on RAW pred. grid (4,4,16), 128x128 tile, K=32
//     per block, 8x8 outputs/thread, XOR-swizzled float4 LDS. Diagonal-tile
//     blocks emit dpart[z][row] (partial ||row||^2). Block (0,0,0) zeroes ctrl.
// ---------------------------------------------------------------------------
__global__ __launch_bounds__(256, 1) void k_gemm(const float* __restrict__ pred,
                                                 float* __restrict__ part,
                                                 float* __restrict__ dpart,
                                                 unsigned int* __restrict__ ctrl) {
    const int tid = threadIdx.x;
    if (blockIdx.x == 0 && blockIdx.y == 0 && blockIdx.z == 0 && tid < 4) ctrl[tid] = 0u;

    __shared__ float4 As4[128][8];
    __shared__ float4 Bs4[128][8];

    const int row0 = blockIdx.y * 128, col0 = blockIdx.x * 128;
    const int z = blockIdx.z;
    const int kz0 = z * 32;

    const int lr = tid >> 1;
    const int sbase = (tid & 1) * 4;
    const int swz = (lr >> 3) & 7;
    const float4* gA = (const float4*)&pred[(row0 + lr) * DE + kz0];
    const float4* gB = (const float4*)&pred[(col0 + lr) * DE + kz0];
#pragma unroll
    for (int q = 0; q < 4; q++) {
        int s = sbase + q;
        As4[lr][s ^ swz] = gA[s];
        Bs4[lr][s ^ swz] = gB[s];
    }
    __syncthreads();

    const int tx = tid & 15, ty = tid >> 4;
    const int aswz = ty & 7, bswz = tx & 7;
    float acc[8][8] = {};

#pragma unroll
    for (int q = 0; q < 8; q++) {
        float4 b4[8];
#pragma unroll
        for (int c = 0; c < 8; c++) b4[c] = Bs4[tx * 8 + c][q ^ bswz];
#pragma unroll
        for (int rr = 0; rr < 2; rr++) {
            float4 a4[4];
#pragma unroll
            for (int r = 0; r < 4; r++) a4[r] = As4[ty * 8 + rr * 4 + r][q ^ aswz];
#pragma unroll
            for (int r = 0; r < 4; r++) {
#pragma unroll
                for (int c = 0; c < 8; c++) {
                    float v = acc[rr * 4 + r][c];
                    v = fmaf(a4[r].x, b4[c].x, v);
                    v = fmaf(a4[r].y, b4[c].y, v);
                    v = fmaf(a4[r].z, b4[c].z, v);
                    v = fmaf(a4[r].w, b4[c].w, v);
                    acc[rr * 4 + r][c] = v;
                }
            }
        }
    }

    float* op = part + (size_t)z * NS * NS;
#pragma unroll
    for (int m = 0; m < 8; m++) {
        float4 o0 = make_float4(acc[m][0], acc[m][1], acc[m][2], acc[m][3]);
        float4 o1 = make_float4(acc[m][4], acc[m][5], acc[m][6], acc[m][7]);
        float* dst = &op[(row0 + ty * 8 + m) * NS + col0 + tx * 8];
        *(float4*)dst = o0;
        *(float4*)(dst + 4) = o1;
    }

    if (blockIdx.x == blockIdx.y && ty == tx) {
#pragma unroll
        for (int m = 0; m < 8; m++)
            dpart[z * NS + row0 + ty * 8 + m] = acc[m][m];
    }
}

// ---------------------------------------------------------------------------
// K2: loss, 256 blocks (1/CU), block b handles anchors iA=b, iB=b+256.
//   rn from dpart once; both anchors' part-rows loaded together (MLP);
//   pass1/pass2 per anchor reusing spart; single combined reduction +
//   one atomic + ticket finalize.
// ---------------------------------------------------------------------------
__global__ __launch_bounds__(256) void k_loss(const float* __restrict__ part,
                                              const float* __restrict__ dpart,
                                              const int* __restrict__ target,
                                              const float* __restrict__ draw,
                                              unsigned int* __restrict__ ctrl,
                                              float* __restrict__ out) {
    const int b = blockIdx.x;
    const int tid = threadIdx.x;
    const int iA = b, iB = b + 256;

    __shared__ float4 v4sA[NS / 4], v4sB[NS / 4];
    __shared__ float  ckA[NS], ckB[NS];
    __shared__ float  rn_s[NS];
    __shared__ int    pkA[NS], pkB[NS];
    __shared__ float  spart[NS * 17];
    __shared__ float  redf[256];
    __shared__ int    redi[256];
    __shared__ unsigned int pcA, pcB;

    float* gsum = (float*)ctrl;
    unsigned int* gnz    = ctrl + 1;
    unsigned int* ticket = ctrl + 2;

    // ---- rn from diag partials (once per block) ----
    float2 d2 = make_float2(0.0f, 0.0f);
#pragma unroll
    for (int z = 0; z < KSPLIT; z++) {
        float2 t2 = ((const float2*)&dpart[z * NS])[tid];
        d2.x += t2.x; d2.y += t2.y;
    }
    const float rn0 = 1.0f / fmaxf(sqrtf(d2.x), 1e-8f);
    const float rn1 = 1.0f / fmaxf(sqrtf(d2.y), 1e-8f);
    const int j0 = tid * 2;
    rn_s[j0] = rn0; rn_s[j0 + 1] = rn1;
    if (tid == 0) { pcA = 0u; pcB = 0u; }

    // ---- both anchors' cos rows, loads interleaved for MLP ----
    float2 gA = make_float2(0.0f, 0.0f), gB = make_float2(0.0f, 0.0f);
#pragma unroll
    for (int z = 0; z < KSPLIT; z++) {
        const float* base = part + (size_t)z * NS * NS;
        float2 tA = ((const float2*)&base[(size_t)iA * NS])[tid];
        float2 tB = ((const float2*)&base[(size_t)iB * NS])[tid];
        gA.x += tA.x; gA.y += tA.y;
        gB.x += tB.x; gB.y += tB.y;
    }

    float cp[NCL];
    cp[0] = 0.0f;
#pragma unroll
    for (int c = 0; c < NCL - 1; c++) cp[c + 1] = cp[c] + log1pf(expf(draw[c]));
    const int tiA = target[iA], tiB = target[iB];
    const float cpA = cp[tiA], cpB = cp[tiB];
    __syncthreads();

    const float rniA = rn_s[iA], rniB = rn_s[iB];
    const int tj0 = target[j0], tj1 = target[j0 + 1];
    const float cpj0 = cp[tj0], cpj1 = cp[tj1];

    // anchor A
    {
        float c0 = gA.x * rniA * rn0;
        float c1 = gA.y * rniA * rn1;
        bool n0 = (tj0 != tiA), n1 = (tj1 != tiA);
        ckA[j0] = c0; ckA[j0 + 1] = c1;
        ((float2*)v4sA)[tid] = make_float2(n0 ? (c0 + fabsf(cpA - cpj0)) : -1e30f,
                                           n1 ? (c1 + fabsf(cpA - cpj1)) : -1e30f);
        if (!n0 && j0 != iA)     pkA[atomicAdd(&pcA, 1u)] = j0;
        if (!n1 && j0 + 1 != iA) pkA[atomicAdd(&pcA, 1u)] = j0 + 1;
        redi[tid] = ((n0 ? 1 : 0) + (n1 ? 1 : 0));
    }
    // anchor B (pack negcounts: A in low 16, B in high 16)
    {
        float c0 = gB.x * rniB * rn0;
        float c1 = gB.y * rniB * rn1;
        bool n0 = (tj0 != tiB), n1 = (tj1 != tiB);
        ckB[j0] = c0; ckB[j0 + 1] = c1;
        ((float2*)v4sB)[tid] = make_float2(n0 ? (c0 + fabsf(cpB - cpj0)) : -1e30f,
                                           n1 ? (c1 + fabsf(cpB - cpj1)) : -1e30f);
        if (!n0 && j0 != iB)     pkB[atomicAdd(&pcB, 1u)] = j0;
        if (!n1 && j0 + 1 != iB) pkB[atomicAdd(&pcB, 1u)] = j0 + 1;
        redi[tid] += ((n0 ? 1 : 0) + (n1 ? 1 : 0)) << 16;
    }
    __syncthreads();
    for (int s = 128; s > 0; s >>= 1) {
        if (tid < s) redi[tid] += redi[tid + s];
        __syncthreads();
    }
    const int negA = redi[0] & 0xffff;
    const int negB = redi[0] >> 16;
    const unsigned int nposA = pcA, nposB = pcB;
    __syncthreads();   // protect redi reuse

    const int kl = tid & 15, jc = tid >> 4;
    const float denA = (float)(negA > 1 ? negA : 1);
    const float denB = (float)(negB > 1 ? negB : 1);
    float contrib = 0.0f;
    int nzc = 0;

    // ===== anchor A =====
    {
        float4 vj[8];
#pragma unroll
        for (int t = 0; t < 8; t++) vj[t] = v4sA[jc * 8 + t];
        for (unsigned int p = kl; p < nposA; p += 16) {
            const float ckp = ckA[pkA[p]];
            float s0 = 0.0f, s1 = 0.0f;
#pragma unroll
            for (int t = 0; t < 8; t++) {
                float4 w = vj[t];
                s0 += fmaxf(w.x - ckp, 0.0f) + fmaxf(w.y - ckp, 0.0f);
                s1 += fmaxf(w.z - ckp, 0.0f) + fmaxf(w.w - ckp, 0.0f);
            }
            spart[p * 17 + jc] = s0 + s1;
        }
        __syncthreads();
        for (unsigned int p = tid; p < nposA; p += 256) {
            float s = 0.0f;
#pragma unroll
            for (int q = 0; q < 16; q++) s += spart[p * 17 + q];
            contrib += s / denA;
            if (s != 0.0f) nzc++;
        }
        __syncthreads();   // spart reuse
    }
    // ===== anchor B =====
    {
        float4 vj[8];
#pragma unroll
        for (int t = 0; t < 8; t++) vj[t] = v4sB[jc * 8 + t];
        for (unsigned int p = kl; p < nposB; p += 16) {
            const float ckp = ckB[pkB[p]];
            float s0 = 0.0f, s1 = 0.0f;
#pragma unroll
            for (int t = 0; t < 8; t++) {
                float4 w = vj[t];
                s0 += fmaxf(w.x - ckp, 0.0f) + fmaxf(w.y - ckp, 0.0f);
                s1 += fmaxf(w.z - ckp, 0.0f) + fmaxf(w.w - ckp, 0.0f);
            }
            spart[p * 17 + jc] = s0 + s1;
        }
        __syncthreads();
        for (unsigned int p = tid; p < nposB; p += 256) {
            float s = 0.0f;
#pragma unroll
            for (int q = 0; q < 16; q++) s += spart[p * 17 + q];
            contrib += s / denB;
            if (s != 0.0f) nzc++;
        }
    }

    // ===== single combined reduction + finalize =====
    redf[tid] = contrib;
    redi[tid] = nzc;
    __syncthreads();
    for (int s = 128; s > 0; s >>= 1) {
        if (tid < s) { redf[tid] += redf[tid + s]; redi[tid] += redi[tid + s]; }
        __syncthreads();
    }
    if (tid == 0) {
        if (redf[0] != 0.0f || redi[0] != 0) {
            atomicAdd(gsum, redf[0]);
            atomicAdd(gnz, (unsigned int)redi[0]);
        }
        __threadfence();
        unsigned int t = atomicAdd(ticket, 1u);
        if (t == (unsigned int)(gridDim.x - 1)) {
            float s = atomicAdd(gsum, 0.0f);
            unsigned int n = atomicAdd(gnz, 0u);
            out[0] = s / (float)(n > 1u ? n : 1u);
        }
    }
}

extern "C" void kernel_launch(void* const* d_in, const int* in_sizes, int n_in,
                              void* d_out, int out_size, void* d_ws, size_t ws_size,
                              hipStream_t stream) {
    const float* pred   = (const float*)d_in[0];
    const float* draw   = (const float*)d_in[1];
    const int*   target = (const int*)d_in[2];
    float* out = (float*)d_out;

    float* ws    = (float*)d_ws;
    float* part  = ws;                                  // 16 MB
    float* dpart = ws + PART_ELEMS;                     // 16*512 floats
    unsigned int* ctrl = (unsigned int*)(dpart + KSPLIT * NS);  // 4 words

    hipLaunchKernelGGL(k_gemm, dim3(4, 4, KSPLIT), dim3(256), 0, stream,
                       pred, part, dpart, ctrl);
    hipLaunchKernelGGL(k_loss, dim3(256), dim3(256), 0, stream,
                       part, dpart, target, draw, ctrl, out);
}